// Round 1
// baseline (379.809 us; speedup 1.0000x reference)
//
#include <hip/hip_runtime.h>

typedef __bf16 bf16x8 __attribute__((ext_vector_type(8)));
typedef __bf16 bf16x4 __attribute__((ext_vector_type(4)));
typedef float f32x4 __attribute__((ext_vector_type(4)));

#define BB 4
#define SS 1024
#define DD 1024
#define HH 16
#define DHH 64
#define FFN 4096

__device__ __forceinline__ void gload_lds16(const void* g, void* lds) {
  __builtin_amdgcn_global_load_lds(
      (const __attribute__((address_space(1))) unsigned int*)g,
      (__attribute__((address_space(3))) unsigned int*)lds, 16, 0, 0);
}

__global__ void cvt_bf16_kernel(const float* __restrict__ in, __bf16* __restrict__ out, int n) {
  int i = (blockIdx.x * 256 + threadIdx.x) * 8;
  if (i >= n) return;
  float4 a = *(const float4*)(in + i);
  float4 b = *(const float4*)(in + i + 4);
  bf16x8 v;
  v[0] = (__bf16)a.x; v[1] = (__bf16)a.y; v[2] = (__bf16)a.z; v[3] = (__bf16)a.w;
  v[4] = (__bf16)b.x; v[5] = (__bf16)b.y; v[6] = (__bf16)b.z; v[7] = (__bf16)b.w;
  *(bf16x8*)(out + i) = v;
}

// MODE 0: out bf16 [B,H,S,DH], v=(acc+bias)*scale   (Q scale=0.125, K scale=1)
// MODE 1: out bf16 [B,H,DH,S], v=acc+bias           (V^T)
// MODE 2: out f32  [M,N],      v=acc+bias+res
// MODE 3: out bf16 [M,N],      v=relu(acc+bias)
template<int MODE>
__global__ __launch_bounds__(256, 2) void gemm_bt(
    const __bf16* __restrict__ A, const __bf16* __restrict__ Bw,
    const float* __restrict__ bias, const float* __restrict__ res,
    void* __restrict__ outp, int M, int N, int K, float scale)
{
  __shared__ __bf16 As[2][128 * 32];
  __shared__ __bf16 Bs[2][128 * 32];
  const int tid = threadIdx.x;
  const int wid = tid >> 6;
  const int lane = tid & 63;
  const int lr = lane & 15;
  const int lg = lane >> 4;
  const int bm = blockIdx.y * 128;
  const int bn = blockIdx.x * 128;
  const int wm = (wid >> 1) * 64;
  const int wn = (wid & 1) * 64;

  // staging: thread t covers LDS byte offset t*16 (+4096 for second half)
  const int off = tid * 16;
  const int srow = off >> 6;          // row within 128-row tile (bf16 row = 64B)
  const int scol = (off & 63) >> 1;   // element col within 32
  const __bf16* gA0 = A + (size_t)(bm + srow) * K + scol;
  const __bf16* gA1 = A + (size_t)(bm + 64 + srow) * K + scol;
  const __bf16* gB0 = Bw + (size_t)(bn + srow) * K + scol;
  const __bf16* gB1 = Bw + (size_t)(bn + 64 + srow) * K + scol;
  char* lA = (char*)&As[0][0] + wid * 1024;  // wave-uniform LDS base (+lane*16 by HW)
  char* lB = (char*)&Bs[0][0] + wid * 1024;

  f32x4 acc[4][4] = {};

#define STAGE(buf, kk) do { \
    gload_lds16(gA0 + (kk), lA + (buf) * 8192); \
    gload_lds16(gA1 + (kk), lA + (buf) * 8192 + 4096); \
    gload_lds16(gB0 + (kk), lB + (buf) * 8192); \
    gload_lds16(gB1 + (kk), lB + (buf) * 8192 + 4096); \
  } while (0)

  STAGE(0, 0);
  __syncthreads();  // compiler drains vmcnt before s_barrier
  const int nk = K >> 5;
  for (int t = 0; t < nk; ++t) {
    const int cur = t & 1;
    if (t + 1 < nk) STAGE(cur ^ 1, (t + 1) << 5);
    bf16x8 af[4], bv[4];
#pragma unroll
    for (int i = 0; i < 4; ++i)
      af[i] = *(const bf16x8*)&As[cur][(wm + i * 16 + lr) * 32 + lg * 8];
#pragma unroll
    for (int i = 0; i < 4; ++i)
      bv[i] = *(const bf16x8*)&Bs[cur][(wn + i * 16 + lr) * 32 + lg * 8];
#pragma unroll
    for (int i = 0; i < 4; ++i)
#pragma unroll
      for (int j = 0; j < 4; ++j)
        acc[i][j] = __builtin_amdgcn_mfma_f32_16x16x32_bf16(af[i], bv[j], acc[i][j], 0, 0, 0);
    __syncthreads();
  }
#undef STAGE

  // epilogue: C/D layout col=lane&15, row=(lane>>4)*4+r  [m89-verified]
#pragma unroll
  for (int i = 0; i < 4; ++i) {
#pragma unroll
    for (int j = 0; j < 4; ++j) {
#pragma unroll
      for (int r = 0; r < 4; ++r) {
        int row = bm + wm + i * 16 + lg * 4 + r;
        int col = bn + wn + j * 16 + lr;
        float v = acc[i][j][r];
        if constexpr (MODE == 0) {
          v = (v + bias[col]) * scale;
          int b_ = row >> 10, s_ = row & 1023;
          int h_ = col >> 6, d_ = col & 63;
          ((__bf16*)outp)[(((size_t)(b_ * HH + h_) * SS) + s_) * DHH + d_] = (__bf16)v;
        } else if constexpr (MODE == 1) {
          v = v + bias[col];
          int b_ = row >> 10, s_ = row & 1023;
          int h_ = col >> 6, d_ = col & 63;
          ((__bf16*)outp)[(((size_t)(b_ * HH + h_) * DHH) + d_) * SS + s_] = (__bf16)v;
        } else if constexpr (MODE == 2) {
          size_t idx = (size_t)row * N + col;
          ((float*)outp)[idx] = v + bias[col] + res[idx];
        } else {
          float t2 = v + bias[col];
          ((__bf16*)outp)[(size_t)row * N + col] = (__bf16)fmaxf(t2, 0.f);
        }
      }
    }
  }
}

// Flash attention: grid = B*H*(S/64), block = 256 (4 waves, 16 q-rows each).
// q,k: bf16 [B*H, S, 64] (q pre-scaled by 1/8); vt: bf16 [B*H, 64, S]; ctx out bf16 [B*S, 1024]
__global__ __launch_bounds__(256, 2) void attn_kernel(
    const __bf16* __restrict__ q, const __bf16* __restrict__ k,
    const __bf16* __restrict__ vt, const int* __restrict__ mask,
    __bf16* __restrict__ ctx)
{
  const int nqb = SS / 64;
  int bh = blockIdx.x / nqb;
  int qb = (blockIdx.x % nqb) * 64;
  int b = bh >> 4;
  int tid = threadIdx.x, wid = tid >> 6, lane = tid & 63;
  int lr = lane & 15, lg = lane >> 4;
  const __bf16* qh = q + (size_t)bh * SS * DHH;
  const __bf16* kh = k + (size_t)bh * SS * DHH;
  const __bf16* vh = vt + (size_t)bh * DHH * SS;

  int qrow = qb + wid * 16;
  bf16x8 qa0 = *(const bf16x8*)&qh[(qrow + lr) * DHH + lg * 8];
  bf16x8 qa1 = *(const bf16x8*)&qh[(qrow + lr) * DHH + 32 + lg * 8];

  __shared__ __bf16 P[4][16 * 32];

  float m[4], l[4], alpha[4];
  f32x4 o[4] = {};
#pragma unroll
  for (int j = 0; j < 4; ++j) { m[j] = -1e30f; l[j] = 0.f; }

  for (int kb = 0; kb < SS; kb += 32) {
    bf16x8 k00 = *(const bf16x8*)&kh[(kb + lr) * DHH + lg * 8];
    bf16x8 k01 = *(const bf16x8*)&kh[(kb + lr) * DHH + 32 + lg * 8];
    bf16x8 k10 = *(const bf16x8*)&kh[(kb + 16 + lr) * DHH + lg * 8];
    bf16x8 k11 = *(const bf16x8*)&kh[(kb + 16 + lr) * DHH + 32 + lg * 8];
    f32x4 z = {};
    f32x4 s0 = __builtin_amdgcn_mfma_f32_16x16x32_bf16(qa0, k00, z, 0, 0, 0);
    s0 = __builtin_amdgcn_mfma_f32_16x16x32_bf16(qa1, k01, s0, 0, 0, 0);
    f32x4 s1 = __builtin_amdgcn_mfma_f32_16x16x32_bf16(qa0, k10, z, 0, 0, 0);
    s1 = __builtin_amdgcn_mfma_f32_16x16x32_bf16(qa1, k11, s1, 0, 0, 0);
    int mk0 = mask[b * SS + kb + lr];
    int mk1 = mask[b * SS + kb + 16 + lr];
    if (mk0 == 0) { s0[0] = -1e20f; s0[1] = -1e20f; s0[2] = -1e20f; s0[3] = -1e20f; }
    if (mk1 == 0) { s1[0] = -1e20f; s1[1] = -1e20f; s1[2] = -1e20f; s1[3] = -1e20f; }
#pragma unroll
    for (int j = 0; j < 4; ++j) {
      float mx = fmaxf(s0[j], s1[j]);
#pragma unroll
      for (int t = 1; t < 16; t <<= 1) mx = fmaxf(mx, __shfl_xor(mx, t));
      float mn = fmaxf(m[j], mx);
      float a = __expf(m[j] - mn);
      float p0 = __expf(s0[j] - mn);
      float p1 = __expf(s1[j] - mn);
      float rs = p0 + p1;
#pragma unroll
      for (int t = 1; t < 16; t <<= 1) rs += __shfl_xor(rs, t);
      l[j] = l[j] * a + rs;
      m[j] = mn;
      alpha[j] = a;
      int prow = lg * 4 + j;
      P[wid][prow * 32 + lr] = (__bf16)p0;
      P[wid][prow * 32 + 16 + lr] = (__bf16)p1;
    }
#pragma unroll
    for (int d = 0; d < 4; ++d)
#pragma unroll
      for (int j = 0; j < 4; ++j) o[d][j] *= alpha[j];
    bf16x8 pa = *(const bf16x8*)&P[wid][lr * 32 + lg * 8];
#pragma unroll
    for (int d = 0; d < 4; ++d) {
      bf16x8 vf = *(const bf16x8*)&vh[(d * 16 + lr) * SS + kb + lg * 8];
      o[d] = __builtin_amdgcn_mfma_f32_16x16x32_bf16(pa, vf, o[d], 0, 0, 0);
    }
  }
#pragma unroll
  for (int j = 0; j < 4; ++j) {
    float inv = 1.f / l[j];
    int srow = qrow + lg * 4 + j;
    size_t base = ((size_t)b * SS + srow) * DD + (bh & 15) * DHH;
#pragma unroll
    for (int d = 0; d < 4; ++d)
      ctx[base + d * 16 + lr] = (__bf16)(o[d][j] * inv);
  }
}

// LayerNorm over D=1024; one block per row; optional bf16 copy, optional mask multiply
__global__ __launch_bounds__(256) void ln_kernel(
    const float* __restrict__ in, const float* __restrict__ g, const float* __restrict__ b,
    const int* __restrict__ mask, float* __restrict__ out32, __bf16* __restrict__ out16,
    int applyMask)
{
  int row = blockIdx.x;
  int tid = threadIdx.x;
  int wid = tid >> 6, lane = tid & 63;
  float4 v = ((const float4*)(in + (size_t)row * DD))[tid];
  float s = v.x + v.y + v.z + v.w;
  float sq = v.x * v.x + v.y * v.y + v.z * v.z + v.w * v.w;
#pragma unroll
  for (int o = 1; o < 64; o <<= 1) { s += __shfl_xor(s, o); sq += __shfl_xor(sq, o); }
  __shared__ float red[8];
  if (lane == 0) { red[wid] = s; red[4 + wid] = sq; }
  __syncthreads();
  s = red[0] + red[1] + red[2] + red[3];
  sq = red[4] + red[5] + red[6] + red[7];
  float mean = s * (1.f / DD);
  float var = sq * (1.f / DD) - mean * mean;
  float rstd = rsqrtf(var + 1e-5f);
  float4 gg = ((const float4*)g)[tid];
  float4 bb = ((const float4*)b)[tid];
  float4 o;
  o.x = (v.x - mean) * rstd * gg.x + bb.x;
  o.y = (v.y - mean) * rstd * gg.y + bb.y;
  o.z = (v.z - mean) * rstd * gg.z + bb.z;
  o.w = (v.w - mean) * rstd * gg.w + bb.w;
  if (applyMask) {
    float mk = (float)mask[row];
    o.x *= mk; o.y *= mk; o.z *= mk; o.w *= mk;
  }
  if (out32) ((float4*)(out32 + (size_t)row * DD))[tid] = o;
  if (out16) {
    bf16x4 w;
    w[0] = (__bf16)o.x; w[1] = (__bf16)o.y; w[2] = (__bf16)o.z; w[3] = (__bf16)o.w;
    *(bf16x4*)(out16 + (size_t)row * DD + tid * 4) = w;
  }
}

extern "C" void kernel_launch(void* const* d_in, const int* in_sizes, int n_in,
                              void* d_out, int out_size, void* d_ws, size_t ws_size,
                              hipStream_t stream) {
  const float* x    = (const float*)d_in[0];
  const int*  mask  = (const int*)d_in[1];
  const float* wq   = (const float*)d_in[2];
  const float* bq   = (const float*)d_in[3];
  const float* wk   = (const float*)d_in[4];
  const float* bk   = (const float*)d_in[5];
  const float* wv   = (const float*)d_in[6];
  const float* bv   = (const float*)d_in[7];
  const float* wo   = (const float*)d_in[8];
  const float* bo   = (const float*)d_in[9];
  const float* ln1g = (const float*)d_in[10];
  const float* ln1b = (const float*)d_in[11];
  const float* w1   = (const float*)d_in[12];
  const float* b1   = (const float*)d_in[13];
  const float* w2   = (const float*)d_in[14];
  const float* b2   = (const float*)d_in[15];
  const float* ln2g = (const float*)d_in[16];
  const float* ln2b = (const float*)d_in[17];
  float* out = (float*)d_out;
  char* ws = (char*)d_ws;

  // workspace layout (bytes); high-water ~104 MB
  __bf16* xb   = (__bf16*)(ws + 0);           // 8 MiB  [4096,1024]
  __bf16* wqb  = (__bf16*)(ws + 8388608);     // 2 MiB
  __bf16* wkb  = (__bf16*)(ws + 10485760);
  __bf16* wvb  = (__bf16*)(ws + 12582912);
  __bf16* wob  = (__bf16*)(ws + 14680064);
  __bf16* w1b  = (__bf16*)(ws + 16777216);    // 8 MiB
  __bf16* w2b  = (__bf16*)(ws + 25165824);    // 8 MiB
  __bf16* qbuf = (__bf16*)(ws + 33554432);    // 8 MiB [B*H,S,64]
  __bf16* kbuf = (__bf16*)(ws + 41943040);
  __bf16* vtbf = (__bf16*)(ws + 50331648);    // [B*H,64,S]
  __bf16* ctxb = (__bf16*)(ws + 58720256);    // [4096,1024]
  __bf16* hb   = (__bf16*)(ws + 33554432);    // 32 MiB [4096,4096]; aliases q/k/vt/ctx (consumed by then)
  float*  r1   = (float*)(ws + 67108864);     // 16 MiB
  float*  t32  = (float*)(ws + 83886080);     // 16 MiB
  __bf16* tb   = (__bf16*)(ws + 100663296);   // 8 MiB
  float*  r2   = r1;                           // reuse (r1 consumed by LN1)

  const int MSD = BB * SS;  // 4096

  // fp32 -> bf16 conversions
  cvt_bf16_kernel<<<2048, 256, 0, stream>>>(x, xb, MSD * DD);
  cvt_bf16_kernel<<<512, 256, 0, stream>>>(wq, wqb, DD * DD);
  cvt_bf16_kernel<<<512, 256, 0, stream>>>(wk, wkb, DD * DD);
  cvt_bf16_kernel<<<512, 256, 0, stream>>>(wv, wvb, DD * DD);
  cvt_bf16_kernel<<<512, 256, 0, stream>>>(wo, wob, DD * DD);
  cvt_bf16_kernel<<<2048, 256, 0, stream>>>(w1, w1b, FFN * DD);
  cvt_bf16_kernel<<<2048, 256, 0, stream>>>(w2, w2b, DD * FFN);

  dim3 g1(DD / 128, MSD / 128);    // (8,32)
  dim3 g2(FFN / 128, MSD / 128);   // (32,32)

  gemm_bt<0><<<g1, 256, 0, stream>>>(xb, wqb, bq, nullptr, qbuf, MSD, DD, DD, 0.125f);
  gemm_bt<0><<<g1, 256, 0, stream>>>(xb, wkb, bk, nullptr, kbuf, MSD, DD, DD, 1.0f);
  gemm_bt<1><<<g1, 256, 0, stream>>>(xb, wvb, bv, nullptr, vtbf, MSD, DD, DD, 1.0f);

  attn_kernel<<<BB * HH * (SS / 64), 256, 0, stream>>>(qbuf, kbuf, vtbf, mask, ctxb);

  gemm_bt<2><<<g1, 256, 0, stream>>>(ctxb, wob, bo, x, r1, MSD, DD, DD, 1.0f);
  ln_kernel<<<MSD, 256, 0, stream>>>(r1, ln1g, ln1b, nullptr, t32, tb, 0);

  gemm_bt<3><<<g2, 256, 0, stream>>>(tb, w1b, b1, nullptr, hb, MSD, FFN, DD, 1.0f);
  gemm_bt<2><<<g1, 256, 0, stream>>>(hb, w2b, b2, t32, r2, MSD, DD, FFN, 1.0f);
  ln_kernel<<<MSD, 256, 0, stream>>>(r2, ln2g, ln2b, mask, out, nullptr, 1);
}

// Round 3
// 367.003 us; speedup vs baseline: 1.0349x; 1.0349x over previous
//
#include <hip/hip_runtime.h>

typedef __bf16 bf16x8 __attribute__((ext_vector_type(8)));
typedef __bf16 bf16x4 __attribute__((ext_vector_type(4)));
typedef float f32x4 __attribute__((ext_vector_type(4)));

#define BB 4
#define SS 1024
#define DD 1024
#define HH 16
#define DHH 64
#define FFN 4096

__device__ __forceinline__ void gload_lds16(const void* g, void* lds) {
  __builtin_amdgcn_global_load_lds(
      (const __attribute__((address_space(1))) unsigned int*)g,
      (__attribute__((address_space(3))) unsigned int*)lds, 16, 0, 0);
}

__global__ void cvt_bf16_kernel(const float* __restrict__ in, __bf16* __restrict__ out, int n) {
  int i = (blockIdx.x * 256 + threadIdx.x) * 8;
  if (i >= n) return;
  float4 a = *(const float4*)(in + i);
  float4 b = *(const float4*)(in + i + 4);
  bf16x8 v;
  v[0] = (__bf16)a.x; v[1] = (__bf16)a.y; v[2] = (__bf16)a.z; v[3] = (__bf16)a.w;
  v[4] = (__bf16)b.x; v[5] = (__bf16)b.y; v[6] = (__bf16)b.z; v[7] = (__bf16)b.w;
  *(bf16x8*)(out + i) = v;
}

// MODE 0: out bf16 [B,H,S,DH], v=(acc+bias)*scale   (Q scale=log2e/8, K scale=1)
// MODE 1: out bf16 [B,H,DH,S], v=acc+bias           (V^T)
// MODE 2: out f32  [M,N],      v=acc+bias+res
// MODE 3: out bf16 [M,N],      v=relu(acc+bias)
template<int MODE>
__global__ __launch_bounds__(256, 2) void gemm_bt(
    const __bf16* __restrict__ A, const __bf16* __restrict__ Bw,
    const float* __restrict__ bias, const float* __restrict__ res,
    void* __restrict__ outp, int M, int N, int K, float scale)
{
  __shared__ __bf16 As[2][128 * 32];
  __shared__ __bf16 Bs[2][128 * 32];
  const int tid = threadIdx.x;
  const int wid = tid >> 6;
  const int lane = tid & 63;
  const int lr = lane & 15;
  const int lg = lane >> 4;

  // XCD-aware chunked block swizzle (nwg % 8 == 0 for all our grids)
  const int gx = gridDim.x;
  const int nwg = gx * gridDim.y;
  const int wg = blockIdx.y * gx + blockIdx.x;
  const int swz = (wg & 7) * (nwg >> 3) + (wg >> 3);
  const int bm = (swz / gx) * 128;
  const int bn = (swz % gx) * 128;

  const int wm = (wid >> 1) * 64;
  const int wn = (wid & 1) * 64;

  // staging: thread t covers LDS byte offset t*16 (+4096 for second half)
  const int off = tid * 16;
  const int srow = off >> 6;          // row within 128-row tile (bf16 row = 64B)
  const int scol = (off & 63) >> 1;   // element col within 32
  const __bf16* gA0 = A + (size_t)(bm + srow) * K + scol;
  const __bf16* gA1 = A + (size_t)(bm + 64 + srow) * K + scol;
  const __bf16* gB0 = Bw + (size_t)(bn + srow) * K + scol;
  const __bf16* gB1 = Bw + (size_t)(bn + 64 + srow) * K + scol;
  char* lA = (char*)&As[0][0] + wid * 1024;  // wave-uniform LDS base (+lane*16 by HW)
  char* lB = (char*)&Bs[0][0] + wid * 1024;

  f32x4 acc[4][4] = {};

#define STAGE(buf, kk) do { \
    gload_lds16(gA0 + (kk), lA + (buf) * 8192); \
    gload_lds16(gA1 + (kk), lA + (buf) * 8192 + 4096); \
    gload_lds16(gB0 + (kk), lB + (buf) * 8192); \
    gload_lds16(gB1 + (kk), lB + (buf) * 8192 + 4096); \
  } while (0)

  STAGE(0, 0);
  __syncthreads();  // compiler drains vmcnt before s_barrier
  const int nk = K >> 5;
  for (int t = 0; t < nk; ++t) {
    const int cur = t & 1;
    if (t + 1 < nk) STAGE(cur ^ 1, (t + 1) << 5);
    bf16x8 af[4], bv[4];
#pragma unroll
    for (int i = 0; i < 4; ++i)
      af[i] = *(const bf16x8*)&As[cur][(wm + i * 16 + lr) * 32 + lg * 8];
#pragma unroll
    for (int i = 0; i < 4; ++i)
      bv[i] = *(const bf16x8*)&Bs[cur][(wn + i * 16 + lr) * 32 + lg * 8];
#pragma unroll
    for (int i = 0; i < 4; ++i)
#pragma unroll
      for (int j = 0; j < 4; ++j)
        acc[i][j] = __builtin_amdgcn_mfma_f32_16x16x32_bf16(af[i], bv[j], acc[i][j], 0, 0, 0);
    __syncthreads();
  }
#undef STAGE

  // epilogue: C/D layout col=lane&15, row=(lane>>4)*4+r  [m89-verified]
#pragma unroll
  for (int i = 0; i < 4; ++i) {
#pragma unroll
    for (int j = 0; j < 4; ++j) {
#pragma unroll
      for (int r = 0; r < 4; ++r) {
        int row = bm + wm + i * 16 + lg * 4 + r;
        int col = bn + wn + j * 16 + lr;
        float v = acc[i][j][r];
        if constexpr (MODE == 0) {
          v = (v + bias[col]) * scale;
          int b_ = row >> 10, s_ = row & 1023;
          int h_ = col >> 6, d_ = col & 63;
          ((__bf16*)outp)[(((size_t)(b_ * HH + h_) * SS) + s_) * DHH + d_] = (__bf16)v;
        } else if constexpr (MODE == 1) {
          v = v + bias[col];
          int b_ = row >> 10, s_ = row & 1023;
          int h_ = col >> 6, d_ = col & 63;
          ((__bf16*)outp)[(((size_t)(b_ * HH + h_) * DHH) + d_) * SS + s_] = (__bf16)v;
        } else if constexpr (MODE == 2) {
          size_t idx = (size_t)row * N + col;
          ((float*)outp)[idx] = v + bias[col] + res[idx];
        } else {
          float t2 = v + bias[col];
          ((__bf16*)outp)[(size_t)row * N + col] = (__bf16)fmaxf(t2, 0.f);
        }
      }
    }
  }
}

// Flash attention, fixed-max softmax (no online rescale, no per-tile cross-lane ops).
// q bf16 [B*H,S,64] pre-scaled by log2e/8 ; k bf16 [B*H,S,64]; vt bf16 [B*H,64,S];
// ctx out bf16 [B*S, 1024].  grid = 1024 blocks (XCD-chunk-swizzled), 4 waves, 16 q-rows/wave.
// p = exp2(s - 23.083) * maskmul ; l accumulated per-lane, reduced once at end.
__global__ __launch_bounds__(256, 3) void attn_kernel(
    const __bf16* __restrict__ q, const __bf16* __restrict__ k,
    const __bf16* __restrict__ vt, const int* __restrict__ mask,
    __bf16* __restrict__ ctx)
{
  const int nwg = gridDim.x;          // 1024
  const int wg = blockIdx.x;
  const int swz = (wg & 7) * (nwg >> 3) + (wg >> 3);
  const int bh = swz >> 4;            // head index [0,64)
  const int qb = (swz & 15) << 6;     // q-block base
  const int b = bh >> 4;

  const int tid = threadIdx.x, wid = tid >> 6, lane = tid & 63;
  const int lr = lane & 15, lg = lane >> 4;
  const int lr7 = lr & 7, lrh = lr >> 3;

  __shared__ float mmulLds[SS];       // mask multiplier per key column (4 KB)
  __shared__ __bf16 P[4][16 * 64];    // per-wave P tile, XOR-swizzled (8 KB)

  {
    const int* mrow = mask + b * SS;
    int c = tid * 4;
    float4 mm;
    mm.x = (float)(mrow[c + 0] != 0);
    mm.y = (float)(mrow[c + 1] != 0);
    mm.z = (float)(mrow[c + 2] != 0);
    mm.w = (float)(mrow[c + 3] != 0);
    ((float4*)mmulLds)[tid] = mm;
  }
  __syncthreads();

  const __bf16* qh = q + (size_t)bh * SS * DHH;
  const __bf16* kh = k + (size_t)bh * SS * DHH;
  const __bf16* vh = vt + (size_t)bh * DHH * SS;
  char* Pw = (char*)&P[wid][0];

  const int qrow = qb + wid * 16;
  bf16x8 qa0 = *(const bf16x8*)&qh[(size_t)(qrow + lr) * DHH + lg * 8];
  bf16x8 qa1 = *(const bf16x8*)&qh[(size_t)(qrow + lr) * DHH + 32 + lg * 8];

  bf16x8 kf[8], vf[8];
  f32x4 o[4] = {};
  float l[4] = {0.f, 0.f, 0.f, 0.f};

#define LOADK(KB) do { \
    _Pragma("unroll") for (int g = 0; g < 4; ++g) \
    _Pragma("unroll") for (int h = 0; h < 2; ++h) \
      kf[g * 2 + h] = *(const bf16x8*)&kh[(size_t)((KB) + g * 16 + lr) * DHH + h * 32 + lg * 8]; \
  } while (0)
#define LOADV(KB) do { \
    _Pragma("unroll") for (int d = 0; d < 4; ++d) \
    _Pragma("unroll") for (int h = 0; h < 2; ++h) \
      vf[d * 2 + h] = *(const bf16x8*)&vh[(size_t)(d * 16 + lr) * SS + (KB) + h * 32 + lg * 8]; \
  } while (0)

  LOADK(0);
  LOADV(0);

#pragma unroll 1
  for (int t = 0; t < SS / 64; ++t) {
    const int kb = t * 64;
    // QK^T: s[g] covers key cols kb+g*16+lr, q-rows lg*4+j
    f32x4 s_[4];
#pragma unroll
    for (int g = 0; g < 4; ++g) {
      f32x4 z = {0.f, 0.f, 0.f, 0.f};
      z = __builtin_amdgcn_mfma_f32_16x16x32_bf16(qa0, kf[g * 2 + 0], z, 0, 0, 0);
      s_[g] = __builtin_amdgcn_mfma_f32_16x16x32_bf16(qa1, kf[g * 2 + 1], z, 0, 0, 0);
    }
    if (t + 1 < SS / 64) LOADK(kb + 64);  // prefetch next K while softmax+PV run

    // p = exp2(s - 23.083) * maskmul; accumulate l; write swizzled P
#pragma unroll
    for (int g = 0; g < 4; ++g) {
      float mm = mmulLds[kb + g * 16 + lr];
#pragma unroll
      for (int j = 0; j < 4; ++j) {
        float p = exp2f(s_[g][j] - 23.0831207f) * mm;
        l[j] += p;
        int row = lg * 4 + j;
        int addr = row * 128 + (((g * 2 + lrh) ^ (row & 7)) << 4) + lr7 * 2;
        *(__bf16*)(Pw + addr) = (__bf16)p;
      }
    }

    // PV: A = P rows lr, k = h*32 + lg*8 + r (swizzle-matched b128 reads, conflict-free)
    bf16x8 pa0 = *(const bf16x8*)(Pw + lr * 128 + (((0 + lg) ^ lr7) << 4));
    bf16x8 pa1 = *(const bf16x8*)(Pw + lr * 128 + (((4 + lg) ^ lr7) << 4));
#pragma unroll
    for (int d = 0; d < 4; ++d) {
      o[d] = __builtin_amdgcn_mfma_f32_16x16x32_bf16(pa0, vf[d * 2 + 0], o[d], 0, 0, 0);
      o[d] = __builtin_amdgcn_mfma_f32_16x16x32_bf16(pa1, vf[d * 2 + 1], o[d], 0, 0, 0);
    }
    if (t + 1 < SS / 64) LOADV(kb + 64);  // prefetch next V (consumed at end of next tile)
  }
#undef LOADK
#undef LOADV

  // one-time l reduction over the 16 lanes of each lg group
#pragma unroll
  for (int j = 0; j < 4; ++j) {
#pragma unroll
    for (int off = 1; off < 16; off <<= 1) l[j] += __shfl_xor(l[j], off);
  }
#pragma unroll
  for (int j = 0; j < 4; ++j) {
    float inv = l[j] > 0.f ? 1.f / l[j] : 0.f;
    int srow = qrow + lg * 4 + j;
    size_t base = ((size_t)b * SS + srow) * DD + (bh & 15) * DHH;
#pragma unroll
    for (int d = 0; d < 4; ++d)
      ctx[base + d * 16 + lr] = (__bf16)(o[d][j] * inv);
  }
}

// LayerNorm over D=1024; one block per row; optional bf16 copy, optional mask multiply
__global__ __launch_bounds__(256) void ln_kernel(
    const float* __restrict__ in, const float* __restrict__ g, const float* __restrict__ b,
    const int* __restrict__ mask, float* __restrict__ out32, __bf16* __restrict__ out16,
    int applyMask)
{
  int row = blockIdx.x;
  int tid = threadIdx.x;
  int wid = tid >> 6, lane = tid & 63;
  float4 v = ((const float4*)(in + (size_t)row * DD))[tid];
  float s = v.x + v.y + v.z + v.w;
  float sq = v.x * v.x + v.y * v.y + v.z * v.z + v.w * v.w;
#pragma unroll
  for (int o = 1; o < 64; o <<= 1) { s += __shfl_xor(s, o); sq += __shfl_xor(sq, o); }
  __shared__ float red[8];
  if (lane == 0) { red[wid] = s; red[4 + wid] = sq; }
  __syncthreads();
  s = red[0] + red[1] + red[2] + red[3];
  sq = red[4] + red[5] + red[6] + red[7];
  float mean = s * (1.f / DD);
  float var = sq * (1.f / DD) - mean * mean;
  float rstd = rsqrtf(var + 1e-5f);
  float4 gg = ((const float4*)g)[tid];
  float4 bb = ((const float4*)b)[tid];
  float4 o;
  o.x = (v.x - mean) * rstd * gg.x + bb.x;
  o.y = (v.y - mean) * rstd * gg.y + bb.y;
  o.z = (v.z - mean) * rstd * gg.z + bb.z;
  o.w = (v.w - mean) * rstd * gg.w + bb.w;
  if (applyMask) {
    float mk = (float)mask[row];
    o.x *= mk; o.y *= mk; o.z *= mk; o.w *= mk;
  }
  if (out32) ((float4*)(out32 + (size_t)row * DD))[tid] = o;
  if (out16) {
    bf16x4 w;
    w[0] = (__bf16)o.x; w[1] = (__bf16)o.y; w[2] = (__bf16)o.z; w[3] = (__bf16)o.w;
    *(bf16x4*)(out16 + (size_t)row * DD + tid * 4) = w;
  }
}

extern "C" void kernel_launch(void* const* d_in, const int* in_sizes, int n_in,
                              void* d_out, int out_size, void* d_ws, size_t ws_size,
                              hipStream_t stream) {
  const float* x    = (const float*)d_in[0];
  const int*  mask  = (const int*)d_in[1];
  const float* wq   = (const float*)d_in[2];
  const float* bq   = (const float*)d_in[3];
  const float* wk   = (const float*)d_in[4];
  const float* bk   = (const float*)d_in[5];
  const float* wv   = (const float*)d_in[6];
  const float* bv   = (const float*)d_in[7];
  const float* wo   = (const float*)d_in[8];
  const float* bo   = (const float*)d_in[9];
  const float* ln1g = (const float*)d_in[10];
  const float* ln1b = (const float*)d_in[11];
  const float* w1   = (const float*)d_in[12];
  const float* b1   = (const float*)d_in[13];
  const float* w2   = (const float*)d_in[14];
  const float* b2   = (const float*)d_in[15];
  const float* ln2g = (const float*)d_in[16];
  const float* ln2b = (const float*)d_in[17];
  float* out = (float*)d_out;
  char* ws = (char*)d_ws;

  // workspace layout (bytes); high-water ~104 MB
  __bf16* xb   = (__bf16*)(ws + 0);           // 8 MiB  [4096,1024]
  __bf16* wqb  = (__bf16*)(ws + 8388608);     // 2 MiB
  __bf16* wkb  = (__bf16*)(ws + 10485760);
  __bf16* wvb  = (__bf16*)(ws + 12582912);
  __bf16* wob  = (__bf16*)(ws + 14680064);
  __bf16* w1b  = (__bf16*)(ws + 16777216);    // 8 MiB
  __bf16* w2b  = (__bf16*)(ws + 25165824);    // 8 MiB
  __bf16* qbuf = (__bf16*)(ws + 33554432);    // 8 MiB [B*H,S,64]
  __bf16* kbuf = (__bf16*)(ws + 41943040);
  __bf16* vtbf = (__bf16*)(ws + 50331648);    // [B*H,64,S]
  __bf16* ctxb = (__bf16*)(ws + 58720256);    // [4096,1024]
  __bf16* hb   = (__bf16*)(ws + 33554432);    // 32 MiB [4096,4096]; aliases q/k/vt/ctx (consumed by then)
  float*  r1   = (float*)(ws + 67108864);     // 16 MiB
  float*  t32  = (float*)(ws + 83886080);     // 16 MiB
  __bf16* tb   = (__bf16*)(ws + 100663296);   // 8 MiB
  float*  r2   = r1;                           // reuse (r1 consumed by LN1)

  const int MSD = BB * SS;  // 4096

  // fp32 -> bf16 conversions
  cvt_bf16_kernel<<<2048, 256, 0, stream>>>(x, xb, MSD * DD);
  cvt_bf16_kernel<<<512, 256, 0, stream>>>(wq, wqb, DD * DD);
  cvt_bf16_kernel<<<512, 256, 0, stream>>>(wk, wkb, DD * DD);
  cvt_bf16_kernel<<<512, 256, 0, stream>>>(wv, wvb, DD * DD);
  cvt_bf16_kernel<<<512, 256, 0, stream>>>(wo, wob, DD * DD);
  cvt_bf16_kernel<<<2048, 256, 0, stream>>>(w1, w1b, FFN * DD);
  cvt_bf16_kernel<<<2048, 256, 0, stream>>>(w2, w2b, DD * FFN);

  dim3 g1(DD / 128, MSD / 128);    // (8,32)
  dim3 g2(FFN / 128, MSD / 128);   // (32,32)

  // Q pre-scaled by (1/8)*log2e so attention can use exp2 with fixed max 16 (e-units)
  gemm_bt<0><<<g1, 256, 0, stream>>>(xb, wqb, bq, nullptr, qbuf, MSD, DD, DD, 0.18033688f);
  gemm_bt<0><<<g1, 256, 0, stream>>>(xb, wkb, bk, nullptr, kbuf, MSD, DD, DD, 1.0f);
  gemm_bt<1><<<g1, 256, 0, stream>>>(xb, wvb, bv, nullptr, vtbf, MSD, DD, DD, 1.0f);

  attn_kernel<<<BB * HH * (SS / 64), 256, 0, stream>>>(qbuf, kbuf, vtbf, mask, ctxb);

  gemm_bt<2><<<g1, 256, 0, stream>>>(ctxb, wob, bo, x, r1, MSD, DD, DD, 1.0f);
  ln_kernel<<<MSD, 256, 0, stream>>>(r1, ln1g, ln1b, nullptr, t32, tb, 0);

  gemm_bt<3><<<g2, 256, 0, stream>>>(tb, w1b, b1, nullptr, hb, MSD, FFN, DD, 1.0f);
  gemm_bt<2><<<g1, 256, 0, stream>>>(hb, w2b, b2, t32, r2, MSD, DD, FFN, 1.0f);
  ln_kernel<<<MSD, 256, 0, stream>>>(r2, ln2g, ln2b, mask, out, nullptr, 1);
}

// Round 4
// 292.819 us; speedup vs baseline: 1.2971x; 1.2533x over previous
//
#include <hip/hip_runtime.h>

typedef __bf16 bf16x8 __attribute__((ext_vector_type(8)));
typedef __bf16 bf16x4 __attribute__((ext_vector_type(4)));
typedef float f32x4 __attribute__((ext_vector_type(4)));
typedef float f32x16 __attribute__((ext_vector_type(16)));

#define BB 4
#define SS 1024
#define DD 1024
#define HH 16
#define DHH 64
#define FFN 4096

__device__ __forceinline__ void gload_lds16(const void* g, void* lds) {
  __builtin_amdgcn_global_load_lds(
      (const __attribute__((address_space(1))) unsigned int*)g,
      (__attribute__((address_space(3))) unsigned int*)lds, 16, 0, 0);
}

__global__ void cvt_bf16_kernel(const float* __restrict__ in, __bf16* __restrict__ out, int n) {
  int i = (blockIdx.x * 256 + threadIdx.x) * 8;
  if (i >= n) return;
  float4 a = *(const float4*)(in + i);
  float4 b = *(const float4*)(in + i + 4);
  bf16x8 v;
  v[0] = (__bf16)a.x; v[1] = (__bf16)a.y; v[2] = (__bf16)a.z; v[3] = (__bf16)a.w;
  v[4] = (__bf16)b.x; v[5] = (__bf16)b.y; v[6] = (__bf16)b.z; v[7] = (__bf16)b.w;
  *(bf16x8*)(out + i) = v;
}

// MODE 0: out bf16 [B,H,S,DH], v=(acc+bias)*scale   (Q scale=log2e/8, K scale=1)
// MODE 1: out bf16 [B,H,DH,S], v=acc+bias           (V^T)
// MODE 2: out f32  [M,N],      v=acc+bias+res
// MODE 3: out bf16 [M,N],      v=relu(acc+bias)
template<int MODE>
__global__ __launch_bounds__(256, 2) void gemm_bt(
    const __bf16* __restrict__ A, const __bf16* __restrict__ Bw,
    const float* __restrict__ bias, const float* __restrict__ res,
    void* __restrict__ outp, int M, int N, int K, float scale)
{
  __shared__ __bf16 As[2][128 * 32];
  __shared__ __bf16 Bs[2][128 * 32];
  const int tid = threadIdx.x;
  const int wid = tid >> 6;
  const int lane = tid & 63;
  const int lr = lane & 15;
  const int lg = lane >> 4;

  // XCD-aware chunked block swizzle (nwg % 8 == 0 for all our grids)
  const int gx = gridDim.x;
  const int nwg = gx * gridDim.y;
  const int wg = blockIdx.y * gx + blockIdx.x;
  const int swz = (wg & 7) * (nwg >> 3) + (wg >> 3);
  const int bm = (swz / gx) * 128;
  const int bn = (swz % gx) * 128;

  const int wm = (wid >> 1) * 64;
  const int wn = (wid & 1) * 64;

  // staging: thread t covers LDS byte offset t*16 (+4096 for second half)
  const int off = tid * 16;
  const int srow = off >> 6;          // row within 128-row tile (bf16 row = 64B)
  const int scol = (off & 63) >> 1;   // element col within 32
  const __bf16* gA0 = A + (size_t)(bm + srow) * K + scol;
  const __bf16* gA1 = A + (size_t)(bm + 64 + srow) * K + scol;
  const __bf16* gB0 = Bw + (size_t)(bn + srow) * K + scol;
  const __bf16* gB1 = Bw + (size_t)(bn + 64 + srow) * K + scol;
  char* lA = (char*)&As[0][0] + wid * 1024;  // wave-uniform LDS base (+lane*16 by HW)
  char* lB = (char*)&Bs[0][0] + wid * 1024;

  f32x4 acc[4][4] = {};

#define STAGE(buf, kk) do { \
    gload_lds16(gA0 + (kk), lA + (buf) * 8192); \
    gload_lds16(gA1 + (kk), lA + (buf) * 8192 + 4096); \
    gload_lds16(gB0 + (kk), lB + (buf) * 8192); \
    gload_lds16(gB1 + (kk), lB + (buf) * 8192 + 4096); \
  } while (0)

  STAGE(0, 0);
  __syncthreads();  // compiler drains vmcnt before s_barrier
  const int nk = K >> 5;
  for (int t = 0; t < nk; ++t) {
    const int cur = t & 1;
    if (t + 1 < nk) STAGE(cur ^ 1, (t + 1) << 5);
    bf16x8 af[4], bv[4];
#pragma unroll
    for (int i = 0; i < 4; ++i)
      af[i] = *(const bf16x8*)&As[cur][(wm + i * 16 + lr) * 32 + lg * 8];
#pragma unroll
    for (int i = 0; i < 4; ++i)
      bv[i] = *(const bf16x8*)&Bs[cur][(wn + i * 16 + lr) * 32 + lg * 8];
#pragma unroll
    for (int i = 0; i < 4; ++i)
#pragma unroll
      for (int j = 0; j < 4; ++j)
        acc[i][j] = __builtin_amdgcn_mfma_f32_16x16x32_bf16(af[i], bv[j], acc[i][j], 0, 0, 0);
    __syncthreads();
  }
#undef STAGE

  // epilogue: C/D layout col=lane&15, row=(lane>>4)*4+r  [m89-verified]
#pragma unroll
  for (int i = 0; i < 4; ++i) {
#pragma unroll
    for (int j = 0; j < 4; ++j) {
#pragma unroll
      for (int r = 0; r < 4; ++r) {
        int row = bm + wm + i * 16 + lg * 4 + r;
        int col = bn + wn + j * 16 + lr;
        float v = acc[i][j][r];
        if constexpr (MODE == 0) {
          v = (v + bias[col]) * scale;
          int b_ = row >> 10, s_ = row & 1023;
          int h_ = col >> 6, d_ = col & 63;
          ((__bf16*)outp)[(((size_t)(b_ * HH + h_) * SS) + s_) * DHH + d_] = (__bf16)v;
        } else if constexpr (MODE == 1) {
          v = v + bias[col];
          int b_ = row >> 10, s_ = row & 1023;
          int h_ = col >> 6, d_ = col & 63;
          ((__bf16*)outp)[(((size_t)(b_ * HH + h_) * DHH) + d_) * SS + s_] = (__bf16)v;
        } else if constexpr (MODE == 2) {
          size_t idx = (size_t)row * N + col;
          ((float*)outp)[idx] = v + bias[col] + res[idx];
        } else {
          float t2 = v + bias[col];
          ((__bf16*)outp)[(size_t)row * N + col] = (__bf16)fmaxf(t2, 0.f);
        }
      }
    }
  }
}

// Flash attention v3: LDS-staged double-buffered K/V (global_load_lds),
// 32x32x16 MFMA, fixed-max softmax, XOR slot-swizzle (slot ^= (row^(row>>3))&7).
// q bf16 [B*H,S,64] pre-scaled by log2e/8; k bf16 [B*H,S,64]; vt bf16 [B*H,64,S];
// ctx out bf16 [B*S,1024]. grid = 512 (64 heads x 8 q-blocks of 128), 4 waves x 32 q-rows.
__global__ __launch_bounds__(256, 2) void attn_kernel(
    const __bf16* __restrict__ q, const __bf16* __restrict__ k,
    const __bf16* __restrict__ vt, const int* __restrict__ mask,
    __bf16* __restrict__ ctx)
{
  const int nwg = gridDim.x;          // 512
  const int wg = blockIdx.x;
  const int swzb = (wg & 7) * (nwg >> 3) + (wg >> 3);
  const int bh = swzb >> 3;           // head [0,64)
  const int qb = (swzb & 7) << 7;     // q-block base (128 rows)
  const int b = bh >> 4;

  const int tid = threadIdx.x, wid = tid >> 6, lane = tid & 63;
  const int ln = lane & 31, hi = lane >> 5;

  __shared__ __bf16 Kt[2][64 * 64];   // 16 KB (keys x d)
  __shared__ __bf16 Vt[2][64 * 64];   // 16 KB (d x keys)
  __shared__ __bf16 Pt[4][32 * 64];   // 16 KB per-wave P tiles
  __shared__ float mmulLds[SS];       // 4 KB

  {
    const int* mrow = mask + b * SS;
    int c = tid * 4;
    float4 mm;
    mm.x = (float)(mrow[c + 0] != 0);
    mm.y = (float)(mrow[c + 1] != 0);
    mm.z = (float)(mrow[c + 2] != 0);
    mm.w = (float)(mrow[c + 3] != 0);
    ((float4*)mmulLds)[tid] = mm;
  }

  const __bf16* qh = q + (size_t)bh * SS * DHH;
  const __bf16* kh = k + (size_t)bh * SS * DHH;
  const __bf16* vh = vt + (size_t)bh * DHH * SS;

  // Q A-fragments (32x32x16): lane holds Q[qw+ln][s*16 + hi*8 + e]
  const int qw = qb + wid * 32;
  bf16x8 qf[4];
#pragma unroll
  for (int s = 0; s < 4; ++s)
    qf[s] = *(const bf16x8*)&qh[(size_t)(qw + ln) * DHH + s * 16 + hi * 8];

  // staging: thread t covers tile rows (t>>3) and (t>>3)+32, 16B slot ps=t&7;
  // source slot pre-swizzled so read-side slot^swz(row) is linear (rule #21)
  const int srow = tid >> 3;
  const int ps = tid & 7;
  const int sw0 = (srow ^ (srow >> 3)) & 7;
  const int r1 = srow + 32;
  const int sw1 = (r1 ^ (r1 >> 3)) & 7;
  const __bf16* kS0 = kh + (size_t)srow * DHH + ((ps ^ sw0) * 8);
  const __bf16* kS1 = kh + (size_t)r1 * DHH + ((ps ^ sw1) * 8);
  const __bf16* vS0 = vh + (size_t)srow * SS + ((ps ^ sw0) * 8);
  const __bf16* vS1 = vh + (size_t)r1 * SS + ((ps ^ sw1) * 8);

#define ASTAGE(bufi, kb_) do { \
    gload_lds16(kS0 + (size_t)(kb_) * DHH, (char*)&Kt[bufi][0] + wid * 1024); \
    gload_lds16(kS1 + (size_t)(kb_) * DHH, (char*)&Kt[bufi][0] + wid * 1024 + 4096); \
    gload_lds16(vS0 + (kb_), (char*)&Vt[bufi][0] + wid * 1024); \
    gload_lds16(vS1 + (kb_), (char*)&Vt[bufi][0] + wid * 1024 + 4096); \
  } while (0)

  char* Pw = (char*)&Pt[wid][0];
  const int swA = (ln ^ (ln >> 3)) & 7;   // swz for tile rows ln (<32)
  const int swB = swA ^ 4;                // swz for tile rows 32+ln

  f32x16 o0 = {}, o1 = {};
  float l[16];
#pragma unroll
  for (int r = 0; r < 16; ++r) l[r] = 0.f;

  ASTAGE(0, 0);
  __syncthreads();   // drains vmcnt; mmulLds also ready

#pragma unroll 1
  for (int t = 0; t < SS / 64; ++t) {
    const int cur = t & 1;
    const int kb = t * 64;
    if (t + 1 < SS / 64) ASTAGE(cur ^ 1, kb + 64);

    const char* Kc = (const char*)&Kt[cur][0];
    const char* Vc = (const char*)&Vt[cur][0];

    // QK^T: sc0 = keys kb+ln (c=0), sc1 = keys kb+32+ln (c=1); rows = q
    f32x16 sc0 = {}, sc1 = {};
#pragma unroll
    for (int s = 0; s < 4; ++s) {
      bf16x8 kb0 = *(const bf16x8*)(Kc + ln * 128 + (((s * 2 + hi) ^ swA) << 4));
      bf16x8 kb1 = *(const bf16x8*)(Kc + (32 + ln) * 128 + (((s * 2 + hi) ^ swB) << 4));
      sc0 = __builtin_amdgcn_mfma_f32_32x32x16_bf16(qf[s], kb0, sc0, 0, 0, 0);
      sc1 = __builtin_amdgcn_mfma_f32_32x32x16_bf16(qf[s], kb1, sc1, 0, 0, 0);
    }

    // softmax (fixed max): p = exp2(s - C) * maskmul; write swizzled P
    float mm0 = mmulLds[kb + ln];
    float mm1 = mmulLds[kb + 32 + ln];
#pragma unroll
    for (int r = 0; r < 16; ++r) {
      float p0 = exp2f(sc0[r] - 23.0831207f) * mm0;
      float p1 = exp2f(sc1[r] - 23.0831207f) * mm1;
      l[r] += p0 + p1;
      int qrow = (r & 3) + 8 * (r >> 2) + 4 * hi;
      int swq = (qrow ^ (qrow >> 3)) & 7;
      *(__bf16*)(Pw + qrow * 128 + ((((ln >> 3) + 0) ^ swq) << 4) + (ln & 7) * 2) = (__bf16)p0;
      *(__bf16*)(Pw + qrow * 128 + ((((ln >> 3) + 4) ^ swq) << 4) + (ln & 7) * 2) = (__bf16)p1;
    }

    // PV: A = P rows q=ln, B = V^T rows d; o0: d=0..31, o1: d=32..63
#pragma unroll
    for (int ks = 0; ks < 4; ++ks) {
      bf16x8 pa = *(const bf16x8*)(Pw + ln * 128 + (((ks * 2 + hi) ^ swA) << 4));
      bf16x8 vb0 = *(const bf16x8*)(Vc + ln * 128 + (((ks * 2 + hi) ^ swA) << 4));
      bf16x8 vb1 = *(const bf16x8*)(Vc + (32 + ln) * 128 + (((ks * 2 + hi) ^ swB) << 4));
      o0 = __builtin_amdgcn_mfma_f32_32x32x16_bf16(pa, vb0, o0, 0, 0, 0);
      o1 = __builtin_amdgcn_mfma_f32_32x32x16_bf16(pa, vb1, o1, 0, 0, 0);
    }
    __syncthreads();
  }
#undef ASTAGE

  // l reduction over key-lanes (ln) within each hi half
#pragma unroll
  for (int r = 0; r < 16; ++r) {
#pragma unroll
    for (int off = 1; off < 32; off <<= 1) l[r] += __shfl_xor(l[r], off);
  }

#pragma unroll
  for (int r = 0; r < 16; ++r) {
    float inv = l[r] > 0.f ? 1.f / l[r] : 0.f;
    int qrow = (r & 3) + 8 * (r >> 2) + 4 * hi;
    size_t base = ((size_t)b * SS + qw + qrow) * DD + (size_t)(bh & 15) * DHH;
    ctx[base + ln] = (__bf16)(o0[r] * inv);
    ctx[base + 32 + ln] = (__bf16)(o1[r] * inv);
  }
}

// LayerNorm over D=1024; one block per row; optional bf16 copy, optional mask multiply
__global__ __launch_bounds__(256) void ln_kernel(
    const float* __restrict__ in, const float* __restrict__ g, const float* __restrict__ b,
    const int* __restrict__ mask, float* __restrict__ out32, __bf16* __restrict__ out16,
    int applyMask)
{
  int row = blockIdx.x;
  int tid = threadIdx.x;
  int wid = tid >> 6, lane = tid & 63;
  float4 v = ((const float4*)(in + (size_t)row * DD))[tid];
  float s = v.x + v.y + v.z + v.w;
  float sq = v.x * v.x + v.y * v.y + v.z * v.z + v.w * v.w;
#pragma unroll
  for (int o = 1; o < 64; o <<= 1) { s += __shfl_xor(s, o); sq += __shfl_xor(sq, o); }
  __shared__ float red[8];
  if (lane == 0) { red[wid] = s; red[4 + wid] = sq; }
  __syncthreads();
  s = red[0] + red[1] + red[2] + red[3];
  sq = red[4] + red[5] + red[6] + red[7];
  float mean = s * (1.f / DD);
  float var = sq * (1.f / DD) - mean * mean;
  float rstd = rsqrtf(var + 1e-5f);
  float4 gg = ((const float4*)g)[tid];
  float4 bb = ((const float4*)b)[tid];
  float4 o;
  o.x = (v.x - mean) * rstd * gg.x + bb.x;
  o.y = (v.y - mean) * rstd * gg.y + bb.y;
  o.z = (v.z - mean) * rstd * gg.z + bb.z;
  o.w = (v.w - mean) * rstd * gg.w + bb.w;
  if (applyMask) {
    float mk = (float)mask[row];
    o.x *= mk; o.y *= mk; o.z *= mk; o.w *= mk;
  }
  if (out32) ((float4*)(out32 + (size_t)row * DD))[tid] = o;
  if (out16) {
    bf16x4 w;
    w[0] = (__bf16)o.x; w[1] = (__bf16)o.y; w[2] = (__bf16)o.z; w[3] = (__bf16)o.w;
    *(bf16x4*)(out16 + (size_t)row * DD + tid * 4) = w;
  }
}

extern "C" void kernel_launch(void* const* d_in, const int* in_sizes, int n_in,
                              void* d_out, int out_size, void* d_ws, size_t ws_size,
                              hipStream_t stream) {
  const float* x    = (const float*)d_in[0];
  const int*  mask  = (const int*)d_in[1];
  const float* wq   = (const float*)d_in[2];
  const float* bq   = (const float*)d_in[3];
  const float* wk   = (const float*)d_in[4];
  const float* bk   = (const float*)d_in[5];
  const float* wv   = (const float*)d_in[6];
  const float* bv   = (const float*)d_in[7];
  const float* wo   = (const float*)d_in[8];
  const float* bo   = (const float*)d_in[9];
  const float* ln1g = (const float*)d_in[10];
  const float* ln1b = (const float*)d_in[11];
  const float* w1   = (const float*)d_in[12];
  const float* b1   = (const float*)d_in[13];
  const float* w2   = (const float*)d_in[14];
  const float* b2   = (const float*)d_in[15];
  const float* ln2g = (const float*)d_in[16];
  const float* ln2b = (const float*)d_in[17];
  float* out = (float*)d_out;
  char* ws = (char*)d_ws;

  // workspace layout (bytes); high-water ~104 MB
  __bf16* xb   = (__bf16*)(ws + 0);           // 8 MiB  [4096,1024]
  __bf16* wqb  = (__bf16*)(ws + 8388608);     // 2 MiB
  __bf16* wkb  = (__bf16*)(ws + 10485760);
  __bf16* wvb  = (__bf16*)(ws + 12582912);
  __bf16* wob  = (__bf16*)(ws + 14680064);
  __bf16* w1b  = (__bf16*)(ws + 16777216);    // 8 MiB
  __bf16* w2b  = (__bf16*)(ws + 25165824);    // 8 MiB
  __bf16* qbuf = (__bf16*)(ws + 33554432);    // 8 MiB [B*H,S,64]
  __bf16* kbuf = (__bf16*)(ws + 41943040);
  __bf16* vtbf = (__bf16*)(ws + 50331648);    // [B*H,64,S]
  __bf16* ctxb = (__bf16*)(ws + 58720256);    // [4096,1024]
  __bf16* hb   = (__bf16*)(ws + 33554432);    // 32 MiB [4096,4096]; aliases q/k/vt/ctx (consumed by then)
  float*  r1   = (float*)(ws + 67108864);     // 16 MiB
  float*  t32  = (float*)(ws + 83886080);     // 16 MiB
  __bf16* tb   = (__bf16*)(ws + 100663296);   // 8 MiB
  float*  r2   = r1;                           // reuse (r1 consumed by LN1)

  const int MSD = BB * SS;  // 4096

  // fp32 -> bf16 conversions
  cvt_bf16_kernel<<<2048, 256, 0, stream>>>(x, xb, MSD * DD);
  cvt_bf16_kernel<<<512, 256, 0, stream>>>(wq, wqb, DD * DD);
  cvt_bf16_kernel<<<512, 256, 0, stream>>>(wk, wkb, DD * DD);
  cvt_bf16_kernel<<<512, 256, 0, stream>>>(wv, wvb, DD * DD);
  cvt_bf16_kernel<<<512, 256, 0, stream>>>(wo, wob, DD * DD);
  cvt_bf16_kernel<<<2048, 256, 0, stream>>>(w1, w1b, FFN * DD);
  cvt_bf16_kernel<<<2048, 256, 0, stream>>>(w2, w2b, DD * FFN);

  dim3 g1(DD / 128, MSD / 128);    // (8,32)
  dim3 g2(FFN / 128, MSD / 128);   // (32,32)

  // Q pre-scaled by (1/8)*log2e so attention can use exp2 with fixed max 16 (e-units)
  gemm_bt<0><<<g1, 256, 0, stream>>>(xb, wqb, bq, nullptr, qbuf, MSD, DD, DD, 0.18033688f);
  gemm_bt<0><<<g1, 256, 0, stream>>>(xb, wkb, bk, nullptr, kbuf, MSD, DD, DD, 1.0f);
  gemm_bt<1><<<g1, 256, 0, stream>>>(xb, wvb, bv, nullptr, vtbf, MSD, DD, DD, 1.0f);

  attn_kernel<<<BB * HH * (SS / 128), 256, 0, stream>>>(qbuf, kbuf, vtbf, mask, ctxb);

  gemm_bt<2><<<g1, 256, 0, stream>>>(ctxb, wob, bo, x, r1, MSD, DD, DD, 1.0f);
  ln_kernel<<<MSD, 256, 0, stream>>>(r1, ln1g, ln1b, nullptr, t32, tb, 0);

  gemm_bt<3><<<g2, 256, 0, stream>>>(tb, w1b, b1, nullptr, hb, MSD, FFN, DD, 1.0f);
  gemm_bt<2><<<g1, 256, 0, stream>>>(hb, w2b, b2, t32, r2, MSD, DD, FFN, 1.0f);
  ln_kernel<<<MSD, 256, 0, stream>>>(r2, ln2g, ln2b, mask, out, nullptr, 1);
}

// Round 5
// 235.825 us; speedup vs baseline: 1.6106x; 1.2417x over previous
//
#include <hip/hip_runtime.h>

typedef __bf16 bf16x8 __attribute__((ext_vector_type(8)));
typedef __bf16 bf16x4 __attribute__((ext_vector_type(4)));
typedef float f32x4 __attribute__((ext_vector_type(4)));
typedef float f32x16 __attribute__((ext_vector_type(16)));

#define BB 4
#define SS 1024
#define DD 1024
#define HH 16
#define DHH 64
#define FFN 4096

__device__ __forceinline__ void gload_lds16(const void* g, void* lds) {
  __builtin_amdgcn_global_load_lds(
      (const __attribute__((address_space(1))) unsigned int*)g,
      (__attribute__((address_space(3))) unsigned int*)lds, 16, 0, 0);
}

// One-shot fp32->bf16 conversion of all inputs. Chunk = 8 elems, 2097152 chunks.
__global__ __launch_bounds__(256) void cvt_all_kernel(
    const float* __restrict__ x, const float* __restrict__ wq, const float* __restrict__ wk,
    const float* __restrict__ wv, const float* __restrict__ wo, const float* __restrict__ w1,
    const float* __restrict__ w2, __bf16* __restrict__ xb, __bf16* __restrict__ wqkvb,
    __bf16* __restrict__ wob, __bf16* __restrict__ w1b, __bf16* __restrict__ w2b)
{
  int i = blockIdx.x * 256 + threadIdx.x;   // chunk index
  const float* src; __bf16* dst; int off;
  if (i < 524288)       { src = x;  dst = xb;              off = i; }
  else if (i < 655360)  { src = wq; dst = wqkvb;           off = i - 524288; }
  else if (i < 786432)  { src = wk; dst = wqkvb + 1048576; off = i - 655360; }
  else if (i < 917504)  { src = wv; dst = wqkvb + 2097152; off = i - 786432; }
  else if (i < 1048576) { src = wo; dst = wob;             off = i - 917504; }
  else if (i < 1572864) { src = w1; dst = w1b;             off = i - 1048576; }
  else                  { src = w2; dst = w2b;             off = i - 1572864; }
  float4 a = *(const float4*)(src + off * 8);
  float4 b = *(const float4*)(src + off * 8 + 4);
  bf16x8 v;
  v[0] = (__bf16)a.x; v[1] = (__bf16)a.y; v[2] = (__bf16)a.z; v[3] = (__bf16)a.w;
  v[4] = (__bf16)b.x; v[5] = (__bf16)b.y; v[6] = (__bf16)b.z; v[7] = (__bf16)b.w;
  *(bf16x8*)(dst + off * 8) = v;
}

// MODE 2: out f32  [M,N],  v=acc+bias+res
// MODE 3: out bf16 [M,N],  v=relu(acc+bias)
// MODE 4: fused QKV: N=3072, col regions {Q,K,V}; Q,K -> [B,H,S,DH]; V -> [B,H,DH,S]
// MODE 5: split-K partial: out f32 [M,N] = raw acc; z = blockIdx.z picks K-range & dst
template<int MODE>
__global__ __launch_bounds__(256, 2) void gemm_bt(
    const __bf16* __restrict__ A, const __bf16* __restrict__ Bw,
    const float* __restrict__ bias, const float* __restrict__ bias1, const float* __restrict__ bias2,
    const float* __restrict__ res, void* __restrict__ outp, void* __restrict__ out1,
    int M, int N, int K, int kLen, float scale)
{
  __shared__ __bf16 As[2][128 * 32];
  __shared__ __bf16 Bs[2][128 * 32];
  const int tid = threadIdx.x;
  const int wid = tid >> 6;
  const int lane = tid & 63;
  const int lr = lane & 15;
  const int lg = lane >> 4;

  // XCD-aware chunked block swizzle (nwg % 8 == 0 for all our grids)
  const int gx = gridDim.x;
  const int nwg = gx * gridDim.y;
  const int wg = blockIdx.y * gx + blockIdx.x;
  const int swz = (wg & 7) * (nwg >> 3) + (wg >> 3);
  const int bm = (swz / gx) * 128;
  const int bn = (swz % gx) * 128;

  const int wm = (wid >> 1) * 64;
  const int wn = (wid & 1) * 64;

  // K-range (MODE 5 splits by blockIdx.z)
  int kBeg = 0, nk = K >> 5;
  if constexpr (MODE == 5) { kBeg = blockIdx.z * kLen; nk = kLen >> 5; }

  // staging: thread t covers LDS byte offset t*16 (+4096 for second half)
  const int off = tid * 16;
  const int srow = off >> 6;          // row within 128-row tile (bf16 row = 64B)
  const int scol = (off & 63) >> 1;   // element col within 32
  const __bf16* gA0 = A + (size_t)(bm + srow) * K + kBeg + scol;
  const __bf16* gA1 = A + (size_t)(bm + 64 + srow) * K + kBeg + scol;
  const __bf16* gB0 = Bw + (size_t)(bn + srow) * K + kBeg + scol;
  const __bf16* gB1 = Bw + (size_t)(bn + 64 + srow) * K + kBeg + scol;
  char* lA = (char*)&As[0][0] + wid * 1024;  // wave-uniform LDS base (+lane*16 by HW)
  char* lB = (char*)&Bs[0][0] + wid * 1024;

  f32x4 acc[4][4] = {};

#define STAGE(buf, kk) do { \
    gload_lds16(gA0 + (kk), lA + (buf) * 8192); \
    gload_lds16(gA1 + (kk), lA + (buf) * 8192 + 4096); \
    gload_lds16(gB0 + (kk), lB + (buf) * 8192); \
    gload_lds16(gB1 + (kk), lB + (buf) * 8192 + 4096); \
  } while (0)

  STAGE(0, 0);
  __syncthreads();  // compiler drains vmcnt before s_barrier
  for (int t = 0; t < nk; ++t) {
    const int cur = t & 1;
    if (t + 1 < nk) STAGE(cur ^ 1, (t + 1) << 5);
    bf16x8 af[4], bv[4];
#pragma unroll
    for (int i = 0; i < 4; ++i)
      af[i] = *(const bf16x8*)&As[cur][(wm + i * 16 + lr) * 32 + lg * 8];
#pragma unroll
    for (int i = 0; i < 4; ++i)
      bv[i] = *(const bf16x8*)&Bs[cur][(wn + i * 16 + lr) * 32 + lg * 8];
#pragma unroll
    for (int i = 0; i < 4; ++i)
#pragma unroll
      for (int j = 0; j < 4; ++j)
        acc[i][j] = __builtin_amdgcn_mfma_f32_16x16x32_bf16(af[i], bv[j], acc[i][j], 0, 0, 0);
    __syncthreads();
  }
#undef STAGE

  // epilogue: C/D layout col=lane&15, row=(lane>>4)*4+r  [m89-verified]
#pragma unroll
  for (int i = 0; i < 4; ++i) {
#pragma unroll
    for (int j = 0; j < 4; ++j) {
#pragma unroll
      for (int r = 0; r < 4; ++r) {
        int row = bm + wm + i * 16 + lg * 4 + r;
        int col = bn + wn + j * 16 + lr;
        float v = acc[i][j][r];
        if constexpr (MODE == 2) {
          size_t idx = (size_t)row * N + col;
          ((float*)outp)[idx] = v + bias[col] + res[idx];
        } else if constexpr (MODE == 3) {
          float t2 = v + bias[col];
          ((__bf16*)outp)[(size_t)row * N + col] = (__bf16)fmaxf(t2, 0.f);
        } else if constexpr (MODE == 4) {
          int region = col >> 10;        // 0=Q 1=K 2=V (uniform per block: bn 128-aligned)
          int col_ = col & 1023;
          int b_ = row >> 10, s_ = row & 1023;
          int h_ = col_ >> 6, d_ = col_ & 63;
          if (region == 0) {
            float v2 = (v + bias[col_]) * scale;   // log2e/8
            ((__bf16*)outp)[(((size_t)(b_ * HH + h_) * SS) + s_) * DHH + d_] = (__bf16)v2;
          } else if (region == 1) {
            float v2 = v + bias1[col_];
            ((__bf16*)out1)[(((size_t)(b_ * HH + h_) * SS) + s_) * DHH + d_] = (__bf16)v2;
          } else {
            float v2 = v + bias2[col_];
            ((__bf16*)res)[(((size_t)(b_ * HH + h_) * DHH) + d_) * SS + s_] = (__bf16)v2;
          }
        } else {  // MODE 5
          float* dst = blockIdx.z ? (float*)out1 : (float*)outp;
          dst[(size_t)row * N + col] = v;
        }
      }
    }
  }
}

// Flash attention v3: LDS-staged double-buffered K/V (global_load_lds),
// 32x32x16 MFMA, fixed-max softmax, XOR slot-swizzle (slot ^= (row^(row>>3))&7).
__global__ __launch_bounds__(256, 2) void attn_kernel(
    const __bf16* __restrict__ q, const __bf16* __restrict__ k,
    const __bf16* __restrict__ vt, const int* __restrict__ mask,
    __bf16* __restrict__ ctx)
{
  const int nwg = gridDim.x;          // 512
  const int wg = blockIdx.x;
  const int swzb = (wg & 7) * (nwg >> 3) + (wg >> 3);
  const int bh = swzb >> 3;           // head [0,64)
  const int qb = (swzb & 7) << 7;     // q-block base (128 rows)
  const int b = bh >> 4;

  const int tid = threadIdx.x, wid = tid >> 6, lane = tid & 63;
  const int ln = lane & 31, hi = lane >> 5;

  __shared__ __bf16 Kt[2][64 * 64];   // 16 KB (keys x d)
  __shared__ __bf16 Vt[2][64 * 64];   // 16 KB (d x keys)
  __shared__ __bf16 Pt[4][32 * 64];   // 16 KB per-wave P tiles
  __shared__ float mmulLds[SS];       // 4 KB

  {
    const int* mrow = mask + b * SS;
    int c = tid * 4;
    float4 mm;
    mm.x = (float)(mrow[c + 0] != 0);
    mm.y = (float)(mrow[c + 1] != 0);
    mm.z = (float)(mrow[c + 2] != 0);
    mm.w = (float)(mrow[c + 3] != 0);
    ((float4*)mmulLds)[tid] = mm;
  }

  const __bf16* qh = q + (size_t)bh * SS * DHH;
  const __bf16* kh = k + (size_t)bh * SS * DHH;
  const __bf16* vh = vt + (size_t)bh * DHH * SS;

  // Q A-fragments (32x32x16): lane holds Q[qw+ln][s*16 + hi*8 + e]
  const int qw = qb + wid * 32;
  bf16x8 qf[4];
#pragma unroll
  for (int s = 0; s < 4; ++s)
    qf[s] = *(const bf16x8*)&qh[(size_t)(qw + ln) * DHH + s * 16 + hi * 8];

  // staging: thread t covers tile rows (t>>3) and (t>>3)+32, 16B slot ps=t&7;
  // source slot pre-swizzled so read-side slot^swz(row) is linear (rule #21)
  const int srow = tid >> 3;
  const int ps = tid & 7;
  const int sw0 = (srow ^ (srow >> 3)) & 7;
  const int r1 = srow + 32;
  const int sw1 = (r1 ^ (r1 >> 3)) & 7;
  const __bf16* kS0 = kh + (size_t)srow * DHH + ((ps ^ sw0) * 8);
  const __bf16* kS1 = kh + (size_t)r1 * DHH + ((ps ^ sw1) * 8);
  const __bf16* vS0 = vh + (size_t)srow * SS + ((ps ^ sw0) * 8);
  const __bf16* vS1 = vh + (size_t)r1 * SS + ((ps ^ sw1) * 8);

#define ASTAGE(bufi, kb_) do { \
    gload_lds16(kS0 + (size_t)(kb_) * DHH, (char*)&Kt[bufi][0] + wid * 1024); \
    gload_lds16(kS1 + (size_t)(kb_) * DHH, (char*)&Kt[bufi][0] + wid * 1024 + 4096); \
    gload_lds16(vS0 + (kb_), (char*)&Vt[bufi][0] + wid * 1024); \
    gload_lds16(vS1 + (kb_), (char*)&Vt[bufi][0] + wid * 1024 + 4096); \
  } while (0)

  char* Pw = (char*)&Pt[wid][0];
  const int swA = (ln ^ (ln >> 3)) & 7;   // swz for tile rows ln (<32)
  const int swB = swA ^ 4;                // swz for tile rows 32+ln

  f32x16 o0 = {}, o1 = {};
  float l[16];
#pragma unroll
  for (int r = 0; r < 16; ++r) l[r] = 0.f;

  ASTAGE(0, 0);
  __syncthreads();   // drains vmcnt; mmulLds also ready

#pragma unroll 1
  for (int t = 0; t < SS / 64; ++t) {
    const int cur = t & 1;
    const int kb = t * 64;
    if (t + 1 < SS / 64) ASTAGE(cur ^ 1, kb + 64);

    const char* Kc = (const char*)&Kt[cur][0];
    const char* Vc = (const char*)&Vt[cur][0];

    // QK^T: sc0 = keys kb+ln (c=0), sc1 = keys kb+32+ln (c=1); rows = q
    f32x16 sc0 = {}, sc1 = {};
#pragma unroll
    for (int s = 0; s < 4; ++s) {
      bf16x8 kb0 = *(const bf16x8*)(Kc + ln * 128 + (((s * 2 + hi) ^ swA) << 4));
      bf16x8 kb1 = *(const bf16x8*)(Kc + (32 + ln) * 128 + (((s * 2 + hi) ^ swB) << 4));
      sc0 = __builtin_amdgcn_mfma_f32_32x32x16_bf16(qf[s], kb0, sc0, 0, 0, 0);
      sc1 = __builtin_amdgcn_mfma_f32_32x32x16_bf16(qf[s], kb1, sc1, 0, 0, 0);
    }

    // softmax (fixed max): p = exp2(s - C) * maskmul; write swizzled P
    float mm0 = mmulLds[kb + ln];
    float mm1 = mmulLds[kb + 32 + ln];
#pragma unroll
    for (int r = 0; r < 16; ++r) {
      float p0 = exp2f(sc0[r] - 23.0831207f) * mm0;
      float p1 = exp2f(sc1[r] - 23.0831207f) * mm1;
      l[r] += p0 + p1;
      int qrow = (r & 3) + 8 * (r >> 2) + 4 * hi;
      int swq = (qrow ^ (qrow >> 3)) & 7;
      *(__bf16*)(Pw + qrow * 128 + ((((ln >> 3) + 0) ^ swq) << 4) + (ln & 7) * 2) = (__bf16)p0;
      *(__bf16*)(Pw + qrow * 128 + ((((ln >> 3) + 4) ^ swq) << 4) + (ln & 7) * 2) = (__bf16)p1;
    }

    // PV: A = P rows q=ln, B = V^T rows d; o0: d=0..31, o1: d=32..63
#pragma unroll
    for (int ks = 0; ks < 4; ++ks) {
      bf16x8 pa = *(const bf16x8*)(Pw + ln * 128 + (((ks * 2 + hi) ^ swA) << 4));
      bf16x8 vb0 = *(const bf16x8*)(Vc + ln * 128 + (((ks * 2 + hi) ^ swA) << 4));
      bf16x8 vb1 = *(const bf16x8*)(Vc + (32 + ln) * 128 + (((ks * 2 + hi) ^ swB) << 4));
      o0 = __builtin_amdgcn_mfma_f32_32x32x16_bf16(pa, vb0, o0, 0, 0, 0);
      o1 = __builtin_amdgcn_mfma_f32_32x32x16_bf16(pa, vb1, o1, 0, 0, 0);
    }
    __syncthreads();
  }
#undef ASTAGE

  // l reduction over key-lanes (ln) within each hi half
#pragma unroll
  for (int r = 0; r < 16; ++r) {
#pragma unroll
    for (int off = 1; off < 32; off <<= 1) l[r] += __shfl_xor(l[r], off);
  }

#pragma unroll
  for (int r = 0; r < 16; ++r) {
    float inv = l[r] > 0.f ? 1.f / l[r] : 0.f;
    int qrow = (r & 3) + 8 * (r >> 2) + 4 * hi;
    size_t base = ((size_t)b * SS + qw + qrow) * DD + (size_t)(bh & 15) * DHH;
    ctx[base + ln] = (__bf16)(o0[r] * inv);
    ctx[base + 32 + ln] = (__bf16)(o1[r] * inv);
  }
}

// LayerNorm over D=1024; one block per row; optional bf16 copy
__global__ __launch_bounds__(256) void ln_kernel(
    const float* __restrict__ in, const float* __restrict__ g, const float* __restrict__ b,
    float* __restrict__ out32, __bf16* __restrict__ out16)
{
  int row = blockIdx.x;
  int tid = threadIdx.x;
  int wid = tid >> 6, lane = tid & 63;
  float4 v = ((const float4*)(in + (size_t)row * DD))[tid];
  float s = v.x + v.y + v.z + v.w;
  float sq = v.x * v.x + v.y * v.y + v.z * v.z + v.w * v.w;
#pragma unroll
  for (int o = 1; o < 64; o <<= 1) { s += __shfl_xor(s, o); sq += __shfl_xor(sq, o); }
  __shared__ float red[8];
  if (lane == 0) { red[wid] = s; red[4 + wid] = sq; }
  __syncthreads();
  s = red[0] + red[1] + red[2] + red[3];
  sq = red[4] + red[5] + red[6] + red[7];
  float mean = s * (1.f / DD);
  float var = sq * (1.f / DD) - mean * mean;
  float rstd = rsqrtf(var + 1e-5f);
  float4 gg = ((const float4*)g)[tid];
  float4 bb = ((const float4*)b)[tid];
  float4 o;
  o.x = (v.x - mean) * rstd * gg.x + bb.x;
  o.y = (v.y - mean) * rstd * gg.y + bb.y;
  o.z = (v.z - mean) * rstd * gg.z + bb.z;
  o.w = (v.w - mean) * rstd * gg.w + bb.w;
  if (out32) ((float4*)(out32 + (size_t)row * DD))[tid] = o;
  if (out16) {
    bf16x4 w;
    w[0] = (__bf16)o.x; w[1] = (__bf16)o.y; w[2] = (__bf16)o.z; w[3] = (__bf16)o.w;
    *(bf16x4*)(out16 + (size_t)row * DD + tid * 4) = w;
  }
}

// LN2 fused with split-K reduce: v = p0 + p1 + bias(b2) + res(t32); LN; mask; -> out f32
__global__ __launch_bounds__(256) void ln2_fused_kernel(
    const float* __restrict__ p0, const float* __restrict__ p1, const float* __restrict__ bias,
    const float* __restrict__ res, const float* __restrict__ g, const float* __restrict__ b,
    const int* __restrict__ mask, float* __restrict__ out)
{
  int row = blockIdx.x;
  int tid = threadIdx.x;
  int wid = tid >> 6, lane = tid & 63;
  size_t base = (size_t)row * DD;
  float4 a0 = ((const float4*)(p0 + base))[tid];
  float4 a1 = ((const float4*)(p1 + base))[tid];
  float4 rr = ((const float4*)(res + base))[tid];
  float4 bs = ((const float4*)bias)[tid];
  float4 v;
  v.x = a0.x + a1.x + rr.x + bs.x;
  v.y = a0.y + a1.y + rr.y + bs.y;
  v.z = a0.z + a1.z + rr.z + bs.z;
  v.w = a0.w + a1.w + rr.w + bs.w;
  float s = v.x + v.y + v.z + v.w;
  float sq = v.x * v.x + v.y * v.y + v.z * v.z + v.w * v.w;
#pragma unroll
  for (int o = 1; o < 64; o <<= 1) { s += __shfl_xor(s, o); sq += __shfl_xor(sq, o); }
  __shared__ float red[8];
  if (lane == 0) { red[wid] = s; red[4 + wid] = sq; }
  __syncthreads();
  s = red[0] + red[1] + red[2] + red[3];
  sq = red[4] + red[5] + red[6] + red[7];
  float mean = s * (1.f / DD);
  float var = sq * (1.f / DD) - mean * mean;
  float rstd = rsqrtf(var + 1e-5f);
  float4 gg = ((const float4*)g)[tid];
  float4 bb = ((const float4*)b)[tid];
  float mk = (float)mask[row];
  float4 o;
  o.x = ((v.x - mean) * rstd * gg.x + bb.x) * mk;
  o.y = ((v.y - mean) * rstd * gg.y + bb.y) * mk;
  o.z = ((v.z - mean) * rstd * gg.z + bb.z) * mk;
  o.w = ((v.w - mean) * rstd * gg.w + bb.w) * mk;
  ((float4*)(out + base))[tid] = o;
}

extern "C" void kernel_launch(void* const* d_in, const int* in_sizes, int n_in,
                              void* d_out, int out_size, void* d_ws, size_t ws_size,
                              hipStream_t stream) {
  const float* x    = (const float*)d_in[0];
  const int*  mask  = (const int*)d_in[1];
  const float* wq   = (const float*)d_in[2];
  const float* bq   = (const float*)d_in[3];
  const float* wk   = (const float*)d_in[4];
  const float* bk   = (const float*)d_in[5];
  const float* wv   = (const float*)d_in[6];
  const float* bv   = (const float*)d_in[7];
  const float* wo   = (const float*)d_in[8];
  const float* bo   = (const float*)d_in[9];
  const float* ln1g = (const float*)d_in[10];
  const float* ln1b = (const float*)d_in[11];
  const float* w1   = (const float*)d_in[12];
  const float* b1   = (const float*)d_in[13];
  const float* w2   = (const float*)d_in[14];
  const float* b2   = (const float*)d_in[15];
  const float* ln2g = (const float*)d_in[16];
  const float* ln2b = (const float*)d_in[17];
  float* out = (float*)d_out;
  char* ws = (char*)d_ws;

  // workspace layout (bytes); high-water ~104 MiB (same as prior rounds)
  __bf16* xb    = (__bf16*)(ws + 0);           // 8 MiB [4096,1024]         (free after QKV gemm)
  __bf16* wqkvb = (__bf16*)(ws + 8388608);     // 6 MiB [3072,1024]         (free after QKV gemm)
  __bf16* wob   = (__bf16*)(ws + 14680064);    // 2 MiB                     (free after WO gemm)
  __bf16* w1b   = (__bf16*)(ws + 16777216);    // 8 MiB
  __bf16* w2b   = (__bf16*)(ws + 25165824);    // 8 MiB
  __bf16* qbuf  = (__bf16*)(ws + 33554432);    // 8 MiB [B*H,S,64]
  __bf16* kbuf  = (__bf16*)(ws + 41943040);    // 8 MiB
  __bf16* vtbf  = (__bf16*)(ws + 50331648);    // 8 MiB [B*H,64,S]
  __bf16* ctxb  = (__bf16*)(ws + 58720256);    // 8 MiB [4096,1024]
  __bf16* hb    = (__bf16*)(ws + 33554432);    // 32 MiB [4096,4096]; aliases q/k/vt/ctx (consumed)
  float*  r1    = (float*)(ws + 67108864);     // 16 MiB (WO out; free after LN1)
  float*  t32   = (float*)(ws + 83886080);     // 16 MiB (LN1 f32 out; res for FFN2)
  __bf16* tb    = (__bf16*)(ws + 100663296);   // 8 MiB  (LN1 bf16 out; free after FFN1)
  float*  p0    = r1;                          // 16 MiB split-K partial z=0 (aliases consumed r1)
  float*  p1    = (float*)(ws + 0);            // 16 MiB split-K partial z=1 (aliases consumed xb/wqkvb)

  const int MSD = BB * SS;  // 4096

  cvt_all_kernel<<<8192, 256, 0, stream>>>(x, wq, wk, wv, wo, w1, w2, xb, wqkvb, wob, w1b, w2b);

  // fused QKV: N=3072, grid (24,32)=768 blocks. Q pre-scaled by (1/8)*log2e for exp2 softmax.
  gemm_bt<4><<<dim3(24, 32), 256, 0, stream>>>(xb, wqkvb, bq, bk, bv, (const float*)vtbf,
                                               qbuf, kbuf, MSD, 3072, DD, 0, 0.18033688f);

  attn_kernel<<<BB * HH * (SS / 128), 256, 0, stream>>>(qbuf, kbuf, vtbf, mask, ctxb);

  // WO: r1 = ctx*wo^T + bo + x
  gemm_bt<2><<<dim3(8, 32), 256, 0, stream>>>(ctxb, wob, bo, nullptr, nullptr, x,
                                              r1, nullptr, MSD, DD, DD, 0, 1.0f);
  ln_kernel<<<MSD, 256, 0, stream>>>(r1, ln1g, ln1b, t32, tb);

  // FFN1: hb = relu(tb*w1^T + b1)
  gemm_bt<3><<<dim3(32, 32), 256, 0, stream>>>(tb, w1b, b1, nullptr, nullptr, nullptr,
                                               hb, nullptr, MSD, FFN, DD, 0, 1.0f);
  // FFN2 split-K=2: p0/p1 = hb*w2^T partials (K halves of 2048)
  gemm_bt<5><<<dim3(8, 32, 2), 256, 0, stream>>>(hb, w2b, nullptr, nullptr, nullptr, nullptr,
                                                 p0, p1, MSD, DD, FFN, 2048, 1.0f);
  // LN2 fused with reduce: out = LN(p0+p1+b2+t32) * mask
  ln2_fused_kernel<<<MSD, 256, 0, stream>>>(p0, p1, b2, t32, ln2g, ln2b, mask, out);
}